// Round 10
// baseline (300.510 us; speedup 1.0000x reference)
//
#include <hip/hip_runtime.h>
#include <stdint.h>

#define NEG (-1e30f)
#define LOG2E 1.4426950408889634f
#define LN2 0.6931471805599453f
#define NS 10     // vocab splits for lse
#define CPB 16    // 16-voc-chunk span per split (ceil(158/10))

typedef __attribute__((ext_vector_type(8))) short bf16x8;
typedef __attribute__((ext_vector_type(4))) float f32x4;

__device__ __forceinline__ unsigned short f2bf(float f) {
  unsigned u = __builtin_bit_cast(unsigned, f);
  unsigned r = u + 0x7FFFu + ((u >> 16) & 1u);
  return (unsigned short)(r >> 16);
}
__device__ __forceinline__ float exp2_fast(float x) {
  float r; asm("v_exp_f32 %0, %1" : "=v"(r) : "v"(x)); return r;
}
__device__ __forceinline__ float log2_fast(float x) {
  float r; asm("v_log_f32 %0, %1" : "=v"(r) : "v"(x)); return r;
}
__device__ __forceinline__ float ldexp_fast(float x, int n) {
  float r; asm("v_ldexp_f32 %0, %1, %2" : "=v"(r) : "v"(x), "v"(n)); return r;
}
// lane l gets lane l-1's value; lane 0 gets 0
__device__ __forceinline__ float dpp_shr1(float x) {
  int r = __builtin_amdgcn_update_dpp(0, __builtin_bit_cast(int, x),
                                      0x138, 0xf, 0xf, false);  // wave_shr:1
  return __builtin_bit_cast(float, r);
}
// lane l gets lane l-1's value; lane 0 keeps its own
__device__ __forceinline__ float dpp_shr1_keep(float x) {
  int xi = __builtin_bit_cast(int, x);
  int r = __builtin_amdgcn_update_dpp(xi, xi, 0x138, 0xf, 0xf, false);
  return __builtin_bit_cast(float, r);
}

// ---------------- prep: f32 -> bf16 ----------------
__global__ void cvt_h_kernel(const float* __restrict__ src,
                             unsigned short* __restrict__ dst, int n4) {
  int i = blockIdx.x * 256 + threadIdx.x;
  if (i >= n4) return;
  float4 v = ((const float4*)src)[i];
  ushort4 o;
  o.x = f2bf(v.x); o.y = f2bf(v.y); o.z = f2bf(v.z); o.w = f2bf(v.w);
  ((ushort4*)dst)[i] = o;
}

__global__ void cvt_w_kernel(const float* __restrict__ W,
                             unsigned short* __restrict__ dst,
                             int V, int D4, int n4) {
  int i = blockIdx.x * 256 + threadIdx.x;
  if (i >= n4) return;
  int row = i / D4;
  ushort4 o = {0, 0, 0, 0};
  if (row < V) {
    float4 v = ((const float4*)W)[i];
    o.x = f2bf(v.x); o.y = f2bf(v.y); o.z = f2bf(v.z); o.w = f2bf(v.w);
  }
  ((ushort4*)dst)[i] = o;
}

// ---------------- kernel 1: fused GEMM + online logsumexp over V ----------------
// 8 waves / 512 threads / 256 M-rows per block (halved W re-reads) x NS=10 vocab
// splits -> 500 blocks = 2 blocks/CU so barrier drains overlap across blocks.
__device__ __forceinline__ void stage32(const unsigned short* Wbf, unsigned char* sbuf,
                                        float* sb, const float* bias, int c, int V, int tid) {
  const unsigned char* base = (const unsigned char*)Wbf + ((size_t)c << 15);
#pragma unroll
  for (int i = 0; i < 4; ++i) {             // 512 threads x 16B x 4 = 32KB
    int dest = (i << 13) + (tid << 4);
    int row = dest >> 10;
    int src = (row << 10) + ((dest & 1023) ^ ((row & 15) << 4));
    __builtin_amdgcn_global_load_lds(
        (const __attribute__((address_space(1))) unsigned int*)(base + src),
        (__attribute__((address_space(3))) unsigned int*)(sbuf + dest), 16, 0, 0);
  }
  if (tid < 32) {
    int vg = (c << 5) + tid;
    sb[tid] = (vg < V) ? bias[vg] : 0.f;
  }
}

__launch_bounds__(512, 4)
__global__ void lse_kernel(const unsigned short* __restrict__ Hbf,
                           const unsigned short* __restrict__ Wbf,
                           const float* __restrict__ bias,
                           float2* __restrict__ lse_p,
                           int V, int NC_tot, int M) {
  __shared__ __align__(16) unsigned char sW[2][32768];
  __shared__ float sbias[2][32];
  const int tid = threadIdx.x;
  const int lane = tid & 63;
  const int w = tid >> 6;                    // 8 waves
  const int vl = lane & 15, kq = lane >> 4;
  const int mblk = blockIdx.x % 50;
  const int split = blockIdx.x / 50;
  const int c0 = split * CPB;
  const int c1 = min(NC_tot, c0 + CPB);
  const int rowbase = mblk * 256 + w * 32;

  bf16x8 bq0[16], bq1[16];
  {
    const unsigned short* h0 = Hbf + (size_t)(rowbase + vl) * 512 + kq * 8;
    const unsigned short* h1 = Hbf + (size_t)(rowbase + 16 + vl) * 512 + kq * 8;
#pragma unroll
    for (int ks = 0; ks < 16; ++ks) {
      bq0[ks] = *(const bf16x8*)(h0 + ks * 32);
      bq1[ks] = *(const bf16x8*)(h1 + ks * 32);
    }
  }

  stage32(Wbf, sW[0], sbias[0], bias, c0, V, tid);
  int cur = 0;
  float mx0 = NEG, sm0 = 0.f, mx1 = NEG, sm1 = 0.f;

  for (int c = c0; c < c1; ++c) {
    asm volatile("s_waitcnt vmcnt(0)" ::: "memory");
    __syncthreads();
    if (c + 1 < c1) stage32(Wbf, sW[cur ^ 1], sbias[cur ^ 1], bias, c + 1, V, tid);

    f32x4 a00 = 0.f, a01 = 0.f, a10 = 0.f, a11 = 0.f;
#pragma unroll
    for (int ks = 0; ks < 16; ++ks) {
      int inrow = (ks * 64 + kq * 16) ^ (vl << 4);
      bf16x8 A0 = *(const bf16x8*)(&sW[cur][(vl << 10) + inrow]);
      bf16x8 A1 = *(const bf16x8*)(&sW[cur][16384 + (vl << 10) + inrow]);
      a00 = __builtin_amdgcn_mfma_f32_16x16x32_bf16(A0, bq0[ks], a00, 0, 0, 0);
      a01 = __builtin_amdgcn_mfma_f32_16x16x32_bf16(A0, bq1[ks], a01, 0, 0, 0);
      a10 = __builtin_amdgcn_mfma_f32_16x16x32_bf16(A1, bq0[ks], a10, 0, 0, 0);
      a11 = __builtin_amdgcn_mfma_f32_16x16x32_bf16(A1, bq1[ks], a11, 0, 0, 0);
    }
    float lg0[8], lg1[8];
#pragma unroll
    for (int g = 0; g < 2; ++g)
#pragma unroll
      for (int j = 0; j < 4; ++j) {
        int vloc = g * 16 + kq * 4 + j;
        bool ok = (c * 32 + vloc) < V;
        float bb = sbias[cur][vloc];
        float x0 = (g == 0) ? a00[j] : a10[j];
        float x1 = (g == 0) ? a01[j] : a11[j];
        lg0[g * 4 + j] = ok ? (x0 + bb) : NEG;
        lg1[g * 4 + j] = ok ? (x1 + bb) : NEG;
      }
    float lm0 = lg0[0], lm1 = lg1[0];
#pragma unroll
    for (int i = 1; i < 8; ++i) { lm0 = fmaxf(lm0, lg0[i]); lm1 = fmaxf(lm1, lg1[i]); }
    float nm0 = fmaxf(mx0, lm0), nm1 = fmaxf(mx1, lm1);
    float s0 = 0.f, s1 = 0.f;
#pragma unroll
    for (int i = 0; i < 8; ++i) { s0 += __expf(lg0[i] - nm0); s1 += __expf(lg1[i] - nm1); }
    sm0 = sm0 * __expf(mx0 - nm0) + s0;  mx0 = nm0;
    sm1 = sm1 * __expf(mx1 - nm1) + s1;  mx1 = nm1;
    cur ^= 1;
  }

#pragma unroll
  for (int d = 16; d <= 32; d <<= 1) {
    float omx = __shfl_xor(mx0, d), osm = __shfl_xor(sm0, d);
    float nm = fmaxf(mx0, omx);
    sm0 = sm0 * __expf(mx0 - nm) + osm * __expf(omx - nm); mx0 = nm;
    omx = __shfl_xor(mx1, d); osm = __shfl_xor(sm1, d);
    nm = fmaxf(mx1, omx);
    sm1 = sm1 * __expf(mx1 - nm) + osm * __expf(omx - nm); mx1 = nm;
  }
  if (lane < 16) {
    lse_p[(size_t)split * M + rowbase + vl]      = make_float2(mx0, sm0);
    lse_p[(size_t)split * M + rowbase + 16 + vl] = make_float2(mx1, sm1);
  }
}

__global__ void lse_merge(const float2* __restrict__ lse_p, float* __restrict__ lse, int M) {
  int i = blockIdx.x * 256 + threadIdx.x;
  if (i >= M) return;
  float mx = NEG, sm = 0.f;
#pragma unroll
  for (int s = 0; s < NS; ++s) {
    float2 p = lse_p[(size_t)s * M + i];
    float nm = fmaxf(mx, p.x);
    sm = sm * __expf(mx - nm) + p.y * __expf(p.x - nm);
    mx = nm;
  }
  lse[i] = mx + __logf(sm);
}

// ---------------- kernel 2: selected logits via gathered-W MFMA GEMM ----------------
// Output row (stride 112): [0..L-1] = exp(logit_lab - logit_blank)  (linear ratio)
//                          [100]    = cb = (logit_blank - lse)*log2e (log2 domain)
//                          [101..103] = 0  (zero pad read by invalid dp lanes)
__launch_bounds__(256, 1)
__global__ void sel_kernel(const unsigned short* __restrict__ Hbf,
                           const unsigned short* __restrict__ Wbf,
                           const float* __restrict__ bias,
                           const int* __restrict__ ys,
                           const float* __restrict__ lse,
                           float* __restrict__ lp,
                           int B, int T, int L) {
  __shared__ __align__(16) unsigned char sWs[114688];  // 112 rows x 1KB
  __shared__ float sb[112];
  const int tid = threadIdx.x, lane = tid & 63, w = tid >> 6;
  const int vl = lane & 15, kq = lane >> 4;
  const int b = blockIdx.x / 7;
  const int mt = blockIdx.x % 7;

  int vocs[28];
#pragma unroll
  for (int i = 0; i < 28; ++i) {
    int n = w * 28 + i;
    vocs[i] = (n < L) ? ys[b * L + n] : 0;
  }
#pragma unroll
  for (int i = 0; i < 28; ++i) {
    int n = w * 28 + i;
    const unsigned char* src = (const unsigned char*)Wbf + ((size_t)vocs[i] << 10);
    int soff = (lane << 4) ^ ((n & 15) << 4);
    __builtin_amdgcn_global_load_lds(
        (const __attribute__((address_space(1))) unsigned int*)(src + soff),
        (__attribute__((address_space(3))) unsigned int*)(sWs + (n << 10) + (lane << 4)), 16, 0, 0);
  }
  if (tid < 112) {
    int voc = (tid < L) ? ys[b * L + tid] : 0;
    sb[tid] = bias[voc];
  }

  const int trow0 = mt * 128 + w * 32;
  bf16x8 bq0[16], bq1[16];
  {
    int t0 = min(trow0 + vl, T - 1), t1 = min(trow0 + 16 + vl, T - 1);
    const unsigned short* h0 = Hbf + (size_t)(b * T + t0) * 512 + kq * 8;
    const unsigned short* h1 = Hbf + (size_t)(b * T + t1) * 512 + kq * 8;
#pragma unroll
    for (int ks = 0; ks < 16; ++ks) {
      bq0[ks] = *(const bf16x8*)(h0 + ks * 32);
      bq1[ks] = *(const bf16x8*)(h1 + ks * 32);
    }
  }
  float ls0 = lse[b * T + min(trow0 + vl, T - 1)];
  float ls1 = lse[b * T + min(trow0 + 16 + vl, T - 1)];

  asm volatile("s_waitcnt vmcnt(0)" ::: "memory");
  __syncthreads();

  f32x4 acc[7][2];
#pragma unroll
  for (int g = 0; g < 7; ++g) { acc[g][0] = 0.f; acc[g][1] = 0.f; }
#pragma unroll
  for (int ks = 0; ks < 16; ++ks) {
    int inrow = (ks * 64 + kq * 16) ^ (vl << 4);
#pragma unroll
    for (int g = 0; g < 7; ++g) {
      bf16x8 A = *(const bf16x8*)(&sWs[((g * 16 + vl) << 10) + inrow]);
      acc[g][0] = __builtin_amdgcn_mfma_f32_16x16x32_bf16(A, bq0[ks], acc[g][0], 0, 0, 0);
      acc[g][1] = __builtin_amdgcn_mfma_f32_16x16x32_bf16(A, bq1[ks], acc[g][1], 0, 0, 0);
    }
  }

  // blank logit+bias lives at n=100 (g=6, kq=1, j=0); broadcast from lane 16+vl
  float bv0, bv1;
  {
    float m0 = acc[6][0][0] + sb[100];
    float m1 = acc[6][1][0] + sb[100];
    bv0 = __shfl(m0, 16 + vl, 64);
    bv1 = __shfl(m1, 16 + vl, 64);
  }

#pragma unroll
  for (int rs = 0; rs < 2; ++rs) {
    int trow = trow0 + rs * 16 + vl;
    if (trow >= T) continue;
    float ls = rs ? ls1 : ls0;
    float bv = rs ? bv1 : bv0;
    float* orow = lp + (size_t)(b * T + trow) * 112;
#pragma unroll
    for (int g = 0; g < 7; ++g) {
      int n0 = g * 16 + kq * 4;
      if (n0 < 100) {
        float4 o;
        o.x = exp2_fast((acc[g][rs][0] + sb[n0 + 0] - bv) * LOG2E);
        o.y = exp2_fast((acc[g][rs][1] + sb[n0 + 1] - bv) * LOG2E);
        o.z = exp2_fast((acc[g][rs][2] + sb[n0 + 2] - bv) * LOG2E);
        o.w = exp2_fast((acc[g][rs][3] + sb[n0 + 3] - bv) * LOG2E);
        *(float4*)(orow + n0) = o;
      } else if (n0 == 100) {
        float4 o = {(bv - ls) * LOG2E, 0.f, 0.f, 0.f};
        *(float4*)(orow + n0) = o;
      }
    }
  }
}

// ---------------- kernel 3: CTC forward DP (exact R7 version, proven) ----------------
#define PH_ISSUE(P, Bk, tb_)                                              \
  _Pragma("unroll") for (int i = 0; i < 16; ++i) {                        \
    int tt = (tb_) + i; tt = (tt < ilen) ? tt : (ilen - 1);               \
    const float* r = lpb + (size_t)tt * 112;                              \
    asm volatile("global_load_dwordx2 %0, %1, off"                        \
                 : "=v"(P[i]) : "v"(r + pidx));                           \
    asm volatile("global_load_dword %0, %1, off"                          \
                 : "=v"(Bk[i]) : "v"(r + L));                             \
  }                                                                       \
  __builtin_amdgcn_sched_barrier(0);

#define DP_STEP(px_, py_, cb_)                                            \
  {                                                                       \
    float pm1 = dpp_shr1(A3);                                             \
    pm1 = ldexp_fast(pm1, dneg);                                          \
    float u1 = A0 + A1; u1 = fmaf(pm1, msk1, u1);                         \
    float u3 = A2 + A3; u3 = fmaf(A1, msk3, u3);                          \
    A0 = A0 + pm1;                                                        \
    A2 = A1 + A2;                                                         \
    A1 = u1 * (px_);                                                      \
    A3 = u3 * (py_);                                                      \
    cbs += (cb_);                                                         \
  }

#define DP_STEP_M(px_, py_, cb_, act)                                     \
  {                                                                       \
    float pm1 = dpp_shr1(A3);                                             \
    pm1 = ldexp_fast(pm1, dneg);                                          \
    float u1 = A0 + A1; u1 = fmaf(pm1, msk1, u1);                         \
    float u3 = A2 + A3; u3 = fmaf(A1, msk3, u3);                          \
    float t0 = A0 + pm1;                                                  \
    float t2 = A1 + A2;                                                   \
    float t1 = u1 * (px_);                                                \
    float t3 = u3 * (py_);                                                \
    if (act) { A0 = t0; A1 = t1; A2 = t2; A3 = t3; cbs += (cb_); }        \
  }

#define RESCALE                                                           \
  {                                                                       \
    float m_ = fmaxf(fmaxf(A0, A1), fmaxf(A2, A3));                       \
    int u_ = __builtin_bit_cast(int, m_);                                 \
    int e_ = u_ >> 23;                                                    \
    bool nz_ = (u_ != 0);                                                 \
    float sc_ = nz_ ? __builtin_bit_cast(float, (254 - e_) << 23) : 1.f;  \
    A0 *= sc_; A1 *= sc_; A2 *= sc_; A3 *= sc_;                           \
    lsc += nz_ ? (float)(e_ - 127) : 0.f;                                 \
    float lp_ = dpp_shr1_keep(lsc);                                       \
    lsc = nz_ ? lsc : lp_;                                                \
    int d_ = (int)(lp_ - lsc);                                            \
    dneg = d_ > 126 ? 126 : d_;                                           \
  }

#define PH_COMP(P, Bk)                                                    \
  _Pragma("unroll") for (int i = 0; i < 16; ++i) {                        \
    DP_STEP(P[i].x, P[i].y, Bk[i])                                        \
    if ((i & 3) == 3) RESCALE                                             \
  }

#define PH_COMP_M(P, Bk, tb_)                                             \
  _Pragma("unroll") for (int i = 0; i < 16; ++i) {                        \
    DP_STEP_M(P[i].x, P[i].y, Bk[i], ((tb_) + i) < ilen)                  \
    if ((i & 3) == 3) RESCALE                                             \
  }

__launch_bounds__(64)
__global__ void ctc_dp_kernel(const float* __restrict__ lp, const int* __restrict__ ys,
                              const int* __restrict__ hlens, const int* __restrict__ olens,
                              float* __restrict__ loss, int T, int L) {
  __shared__ float arr[256];
  __shared__ float lscarr[64];
  const int b = blockIdx.x;
  const int lane = threadIdx.x;
  const int ilen = hlens[b];
  const int Smax = 2 * L;

  float msk1, msk3;
  {
    int s1 = 4 * lane + 1, s3 = 4 * lane + 3;
    int i1 = min((s1 - 1) >> 1, L - 1), i1p = max(0, min((s1 - 3) >> 1, L - 1));
    int i3 = min((s3 - 1) >> 1, L - 1), i3p = max(0, min((s3 - 3) >> 1, L - 1));
    int lab1 = ys[b * L + i1], lab1p = ys[b * L + i1p];
    int lab3 = ys[b * L + i3], lab3p = ys[b * L + i3p];
    msk1 = ((s1 <= Smax) && (s1 >= 3) && (lab1 != lab1p)) ? 1.f : 0.f;
    msk3 = ((s3 <= Smax) && (s3 >= 3) && (lab3 != lab3p)) ? 1.f : 0.f;
  }
  const int lim = (Smax - 3) >> 2;
  const int pidx = (lane <= lim) ? 2 * lane : (L + 2);

  const float* lpb = lp + (size_t)(b * T) * 112;

  float A0 = (lane == 0) ? 1.f : 0.f, A1 = 0.f, A2 = 0.f, A3 = 0.f;
  float lsc = 0.f, cbs = 0.f;
  int dneg = 0;

  float2 pA[16], pB[16], pC[16];
  float bA[16], bB[16], bC[16];
  const int nph = (ilen + 15) >> 4;

  PH_ISSUE(pA, bA, 0)
  PH_ISSUE(pB, bB, 16)
  for (int k = 0; k < nph; ++k) {
    const int tb = k << 4;
    asm volatile("s_waitcnt vmcnt(32)" ::: "memory");
    __builtin_amdgcn_sched_barrier(0);
    const int m3 = k - (k / 3) * 3;
    const bool lastm = (k == nph - 1);
    if (m3 == 0) {
      PH_ISSUE(pC, bC, tb + 32)
      if (lastm) { PH_COMP_M(pA, bA, tb) } else { PH_COMP(pA, bA) }
    } else if (m3 == 1) {
      PH_ISSUE(pA, bA, tb + 32)
      if (lastm) { PH_COMP_M(pB, bB, tb) } else { PH_COMP(pB, bB) }
    } else {
      PH_ISSUE(pB, bB, tb + 32)
      if (lastm) { PH_COMP_M(pC, bC, tb) } else { PH_COMP(pC, bC) }
    }
  }
  asm volatile("s_waitcnt vmcnt(0)" ::: "memory");
  __builtin_amdgcn_sched_barrier(0);

  arr[lane * 4 + 0] = A0; arr[lane * 4 + 1] = A1;
  arr[lane * 4 + 2] = A2; arr[lane * 4 + 3] = A3;
  lscarr[lane] = lsc;
  __syncthreads();
  if (lane == 0) {
    int ol = olens[b];
    float aN = arr[2 * ol], aNm = arr[2 * ol - 1];
    float l1 = lscarr[(2 * ol) >> 2], l2 = lscarr[(2 * ol - 1) >> 2];
    float mm = fmaxf(l1, l2);
    float v = ldexp_fast(aN, (int)(l1 - mm)) + ldexp_fast(aNm, (int)(l2 - mm));
    loss[b] = -LN2 * (log2_fast(v) + mm + cbs);
  }
}

__global__ void finalize_kernel(const float* __restrict__ loss, float* __restrict__ out, int B) {
  float v = ((int)threadIdx.x < B) ? loss[threadIdx.x] : 0.f;
#pragma unroll
  for (int m = 1; m <= 32; m <<= 1) v += __shfl_xor(v, m);
  if (threadIdx.x == 0) out[0] = v / (float)B;
}

extern "C" void kernel_launch(void* const* d_in, const int* in_sizes, int n_in,
                              void* d_out, int out_size, void* d_ws, size_t ws_size,
                              hipStream_t stream) {
  const float* hs    = (const float*)d_in[0];
  const int*   hlens = (const int*)d_in[1];
  const int*   ys    = (const int*)d_in[2];
  const int*   olens = (const int*)d_in[3];
  const float* W     = (const float*)d_in[4];
  const float* bias  = (const float*)d_in[5];

  int B = in_sizes[1];              // 16
  int L = in_sizes[2] / B;          // 100
  int V = in_sizes[5];              // 5000
  int D = in_sizes[4] / V;          // 512
  int T = in_sizes[0] / (B * D);    // 800
  int Vp = (V + 63) & ~63;          // 5056
  int M = B * T;                    // 12800
  int NC_tot = Vp / 32;             // 158

  char* ws = (char*)d_ws;
  unsigned short* Hbf = (unsigned short*)ws;
  size_t off = (size_t)M * D * 2;
  unsigned short* Wbf = (unsigned short*)(ws + off);
  off += (size_t)Vp * D * 2;
  float* lse = (float*)(ws + off);
  off += (size_t)M * 4;
  off = (off + 255) & ~(size_t)255;
  float2* lse_p = (float2*)(ws + off);
  off += (size_t)NS * M * 8;
  off = (off + 255) & ~(size_t)255;
  float* lp = (float*)(ws + off);
  off += (size_t)M * 112 * 4;
  float* loss = (float*)(ws + off);

  int n4h = M * D / 4;
  cvt_h_kernel<<<(n4h + 255) / 256, 256, 0, stream>>>(hs, Hbf, n4h);
  int n4w = Vp * D / 4;
  cvt_w_kernel<<<(n4w + 255) / 256, 256, 0, stream>>>(W, Wbf, V, D / 4, n4w);
  lse_kernel<<<50 * NS, 512, 0, stream>>>(Hbf, Wbf, bias, lse_p, V, NC_tot, M);
  lse_merge<<<(M + 255) / 256, 256, 0, stream>>>(lse_p, lse, M);
  sel_kernel<<<B * 7, 256, 0, stream>>>(Hbf, Wbf, bias, ys, lse, lp, B, T, L);
  ctc_dp_kernel<<<B, 64, 0, stream>>>(lp, ys, hlens, olens, loss, T, L);
  finalize_kernel<<<1, 64, 0, stream>>>(loss, (float*)d_out, B);
}

// Round 12
// 199.748 us; speedup vs baseline: 1.5044x; 1.5044x over previous
//
#include <hip/hip_runtime.h>
#include <stdint.h>

#define NEG (-1e30f)
#define LOG2E 1.4426950408889634f
#define LN2 0.6931471805599453f
#define NS 5      // vocab splits for lse
#define CPB 32    // 32-voc chunks per split (ceil(158/5))

typedef __attribute__((ext_vector_type(8))) short bf16x8;
typedef __attribute__((ext_vector_type(4))) float f32x4;

__device__ __forceinline__ unsigned short f2bf(float f) {
  unsigned u = __builtin_bit_cast(unsigned, f);
  unsigned r = u + 0x7FFFu + ((u >> 16) & 1u);
  return (unsigned short)(r >> 16);
}
__device__ __forceinline__ float exp2_fast(float x) {
  float r; asm("v_exp_f32 %0, %1" : "=v"(r) : "v"(x)); return r;
}
__device__ __forceinline__ float log2_fast(float x) {
  float r; asm("v_log_f32 %0, %1" : "=v"(r) : "v"(x)); return r;
}
__device__ __forceinline__ float ldexp_fast(float x, int n) {
  float r; asm("v_ldexp_f32 %0, %1, %2" : "=v"(r) : "v"(x), "v"(n)); return r;
}
// lane l gets lane l-1's value; lane 0 gets 0
__device__ __forceinline__ float dpp_shr1(float x) {
  int r = __builtin_amdgcn_update_dpp(0, __builtin_bit_cast(int, x),
                                      0x138, 0xf, 0xf, false);  // wave_shr:1
  return __builtin_bit_cast(float, r);
}
// lane l gets lane l-1's value; lane 0 keeps its own
__device__ __forceinline__ float dpp_shr1_keep(float x) {
  int xi = __builtin_bit_cast(int, x);
  int r = __builtin_amdgcn_update_dpp(xi, xi, 0x138, 0xf, 0xf, false);
  return __builtin_bit_cast(float, r);
}

// ---------------- prep: f32 -> bf16 ----------------
__global__ void cvt_h_kernel(const float* __restrict__ src,
                             unsigned short* __restrict__ dst, int n4) {
  int i = blockIdx.x * 256 + threadIdx.x;
  if (i >= n4) return;
  float4 v = ((const float4*)src)[i];
  ushort4 o;
  o.x = f2bf(v.x); o.y = f2bf(v.y); o.z = f2bf(v.z); o.w = f2bf(v.w);
  ((ushort4*)dst)[i] = o;
}

__global__ void cvt_w_kernel(const float* __restrict__ W,
                             unsigned short* __restrict__ dst,
                             int V, int D4, int n4) {
  int i = blockIdx.x * 256 + threadIdx.x;
  if (i >= n4) return;
  int row = i / D4;
  ushort4 o = {0, 0, 0, 0};
  if (row < V) {
    float4 v = ((const float4*)W)[i];
    o.x = f2bf(v.x); o.y = f2bf(v.y); o.z = f2bf(v.z); o.w = f2bf(v.w);
  }
  ((ushort4*)dst)[i] = o;
}

// ---------------- kernel 1: fused GEMM + online logsumexp over V (R7 proven config) ----------------
__device__ __forceinline__ void stage32(const unsigned short* Wbf, unsigned char* sbuf,
                                        float* sb, const float* bias, int c, int V, int tid) {
  const unsigned char* base = (const unsigned char*)Wbf + ((size_t)c << 15);
#pragma unroll
  for (int i = 0; i < 8; ++i) {
    int dest = (i << 12) + (tid << 4);
    int row = dest >> 10;
    int src = (row << 10) + ((dest & 1023) ^ ((row & 15) << 4));
    __builtin_amdgcn_global_load_lds(
        (const __attribute__((address_space(1))) unsigned int*)(base + src),
        (__attribute__((address_space(3))) unsigned int*)(sbuf + dest), 16, 0, 0);
  }
  if (tid < 32) {
    int vg = (c << 5) + tid;
    sb[tid] = (vg < V) ? bias[vg] : 0.f;
  }
}

__launch_bounds__(256, 2)
__global__ void lse_kernel(const unsigned short* __restrict__ Hbf,
                           const unsigned short* __restrict__ Wbf,
                           const float* __restrict__ bias,
                           float2* __restrict__ lse_p,
                           int V, int NC_tot, int M) {
  __shared__ __align__(16) unsigned char sW[2][32768];
  __shared__ float sbias[2][32];
  const int tid = threadIdx.x;
  const int lane = tid & 63;
  const int w = tid >> 6;
  const int vl = lane & 15, kq = lane >> 4;
  const int mblk = blockIdx.x % 100;
  const int split = blockIdx.x / 100;
  const int c0 = split * CPB;
  const int c1 = min(NC_tot, c0 + CPB);
  const int rowbase = mblk * 128 + w * 32;

  bf16x8 bq0[16], bq1[16];
  {
    const unsigned short* h0 = Hbf + (size_t)(rowbase + vl) * 512 + kq * 8;
    const unsigned short* h1 = Hbf + (size_t)(rowbase + 16 + vl) * 512 + kq * 8;
#pragma unroll
    for (int ks = 0; ks < 16; ++ks) {
      bq0[ks] = *(const bf16x8*)(h0 + ks * 32);
      bq1[ks] = *(const bf16x8*)(h1 + ks * 32);
    }
  }

  stage32(Wbf, sW[0], sbias[0], bias, c0, V, tid);
  int cur = 0;
  float mx0 = NEG, sm0 = 0.f, mx1 = NEG, sm1 = 0.f;

  for (int c = c0; c < c1; ++c) {
    asm volatile("s_waitcnt vmcnt(0)" ::: "memory");
    __syncthreads();
    if (c + 1 < c1) stage32(Wbf, sW[cur ^ 1], sbias[cur ^ 1], bias, c + 1, V, tid);

    f32x4 a00 = 0.f, a01 = 0.f, a10 = 0.f, a11 = 0.f;
#pragma unroll
    for (int ks = 0; ks < 16; ++ks) {
      int inrow = (ks * 64 + kq * 16) ^ (vl << 4);
      bf16x8 A0 = *(const bf16x8*)(&sW[cur][(vl << 10) + inrow]);
      bf16x8 A1 = *(const bf16x8*)(&sW[cur][16384 + (vl << 10) + inrow]);
      a00 = __builtin_amdgcn_mfma_f32_16x16x32_bf16(A0, bq0[ks], a00, 0, 0, 0);
      a01 = __builtin_amdgcn_mfma_f32_16x16x32_bf16(A0, bq1[ks], a01, 0, 0, 0);
      a10 = __builtin_amdgcn_mfma_f32_16x16x32_bf16(A1, bq0[ks], a10, 0, 0, 0);
      a11 = __builtin_amdgcn_mfma_f32_16x16x32_bf16(A1, bq1[ks], a11, 0, 0, 0);
    }
    float lg0[8], lg1[8];
#pragma unroll
    for (int g = 0; g < 2; ++g)
#pragma unroll
      for (int j = 0; j < 4; ++j) {
        int vloc = g * 16 + kq * 4 + j;
        bool ok = (c * 32 + vloc) < V;
        float bb = sbias[cur][vloc];
        float x0 = (g == 0) ? a00[j] : a10[j];
        float x1 = (g == 0) ? a01[j] : a11[j];
        lg0[g * 4 + j] = ok ? (x0 + bb) : NEG;
        lg1[g * 4 + j] = ok ? (x1 + bb) : NEG;
      }
    float lm0 = lg0[0], lm1 = lg1[0];
#pragma unroll
    for (int i = 1; i < 8; ++i) { lm0 = fmaxf(lm0, lg0[i]); lm1 = fmaxf(lm1, lg1[i]); }
    float nm0 = fmaxf(mx0, lm0), nm1 = fmaxf(mx1, lm1);
    float s0 = 0.f, s1 = 0.f;
#pragma unroll
    for (int i = 0; i < 8; ++i) { s0 += __expf(lg0[i] - nm0); s1 += __expf(lg1[i] - nm1); }
    sm0 = sm0 * __expf(mx0 - nm0) + s0;  mx0 = nm0;
    sm1 = sm1 * __expf(mx1 - nm1) + s1;  mx1 = nm1;
    cur ^= 1;
  }

#pragma unroll
  for (int d = 16; d <= 32; d <<= 1) {
    float omx = __shfl_xor(mx0, d), osm = __shfl_xor(sm0, d);
    float nm = fmaxf(mx0, omx);
    sm0 = sm0 * __expf(mx0 - nm) + osm * __expf(omx - nm); mx0 = nm;
    omx = __shfl_xor(mx1, d); osm = __shfl_xor(sm1, d);
    nm = fmaxf(mx1, omx);
    sm1 = sm1 * __expf(mx1 - nm) + osm * __expf(omx - nm); mx1 = nm;
  }
  if (lane < 16) {
    lse_p[(size_t)split * M + rowbase + vl]      = make_float2(mx0, sm0);
    lse_p[(size_t)split * M + rowbase + 16 + vl] = make_float2(mx1, sm1);
  }
}

__global__ void lse_merge(const float2* __restrict__ lse_p, float* __restrict__ lse, int M) {
  int i = blockIdx.x * 256 + threadIdx.x;
  if (i >= M) return;
  float mx = NEG, sm = 0.f;
#pragma unroll
  for (int s = 0; s < NS; ++s) {
    float2 p = lse_p[(size_t)s * M + i];
    float nm = fmaxf(mx, p.x);
    sm = sm * __expf(mx - nm) + p.y * __expf(p.x - nm);
    mx = nm;
  }
  lse[i] = mx + __logf(sm);
}

// ---------------- kernel 2: selected logits via gathered-W MFMA GEMM ----------------
// Output row (stride 112): [0..L-1] = exp(logit_lab - logit_blank)  (linear ratio)
//                          [100]    = cb = (logit_blank - lse)*log2e (log2 domain)
//                          [101..103] = 0  (zero pad read by invalid dp lanes)
__launch_bounds__(256, 1)
__global__ void sel_kernel(const unsigned short* __restrict__ Hbf,
                           const unsigned short* __restrict__ Wbf,
                           const float* __restrict__ bias,
                           const int* __restrict__ ys,
                           const float* __restrict__ lse,
                           float* __restrict__ lp,
                           int B, int T, int L) {
  __shared__ __align__(16) unsigned char sWs[114688];  // 112 rows x 1KB
  __shared__ float sb[112];
  const int tid = threadIdx.x, lane = tid & 63, w = tid >> 6;
  const int vl = lane & 15, kq = lane >> 4;
  const int b = blockIdx.x / 7;
  const int mt = blockIdx.x % 7;

  int vocs[28];
#pragma unroll
  for (int i = 0; i < 28; ++i) {
    int n = w * 28 + i;
    vocs[i] = (n < L) ? ys[b * L + n] : 0;
  }
#pragma unroll
  for (int i = 0; i < 28; ++i) {
    int n = w * 28 + i;
    const unsigned char* src = (const unsigned char*)Wbf + ((size_t)vocs[i] << 10);
    int soff = (lane << 4) ^ ((n & 15) << 4);
    __builtin_amdgcn_global_load_lds(
        (const __attribute__((address_space(1))) unsigned int*)(src + soff),
        (__attribute__((address_space(3))) unsigned int*)(sWs + (n << 10) + (lane << 4)), 16, 0, 0);
  }
  if (tid < 112) {
    int voc = (tid < L) ? ys[b * L + tid] : 0;
    sb[tid] = bias[voc];
  }

  const int trow0 = mt * 128 + w * 32;
  bf16x8 bq0[16], bq1[16];
  {
    int t0 = min(trow0 + vl, T - 1), t1 = min(trow0 + 16 + vl, T - 1);
    const unsigned short* h0 = Hbf + (size_t)(b * T + t0) * 512 + kq * 8;
    const unsigned short* h1 = Hbf + (size_t)(b * T + t1) * 512 + kq * 8;
#pragma unroll
    for (int ks = 0; ks < 16; ++ks) {
      bq0[ks] = *(const bf16x8*)(h0 + ks * 32);
      bq1[ks] = *(const bf16x8*)(h1 + ks * 32);
    }
  }
  float ls0 = lse[b * T + min(trow0 + vl, T - 1)];
  float ls1 = lse[b * T + min(trow0 + 16 + vl, T - 1)];

  asm volatile("s_waitcnt vmcnt(0)" ::: "memory");
  __syncthreads();

  f32x4 acc[7][2];
#pragma unroll
  for (int g = 0; g < 7; ++g) { acc[g][0] = 0.f; acc[g][1] = 0.f; }
#pragma unroll
  for (int ks = 0; ks < 16; ++ks) {
    int inrow = (ks * 64 + kq * 16) ^ (vl << 4);
#pragma unroll
    for (int g = 0; g < 7; ++g) {
      bf16x8 A = *(const bf16x8*)(&sWs[((g * 16 + vl) << 10) + inrow]);
      acc[g][0] = __builtin_amdgcn_mfma_f32_16x16x32_bf16(A, bq0[ks], acc[g][0], 0, 0, 0);
      acc[g][1] = __builtin_amdgcn_mfma_f32_16x16x32_bf16(A, bq1[ks], acc[g][1], 0, 0, 0);
    }
  }

  // blank logit+bias lives at n=100 (g=6, kq=1, j=0); broadcast from lane 16+vl
  float bv0, bv1;
  {
    float m0 = acc[6][0][0] + sb[100];
    float m1 = acc[6][1][0] + sb[100];
    bv0 = __shfl(m0, 16 + vl, 64);
    bv1 = __shfl(m1, 16 + vl, 64);
  }

#pragma unroll
  for (int rs = 0; rs < 2; ++rs) {
    int trow = trow0 + rs * 16 + vl;
    if (trow >= T) continue;
    float ls = rs ? ls1 : ls0;
    float bv = rs ? bv1 : bv0;
    float* orow = lp + (size_t)(b * T + trow) * 112;
#pragma unroll
    for (int g = 0; g < 7; ++g) {
      int n0 = g * 16 + kq * 4;
      if (n0 < 100) {
        float4 o;
        o.x = exp2_fast((acc[g][rs][0] + sb[n0 + 0] - bv) * LOG2E);
        o.y = exp2_fast((acc[g][rs][1] + sb[n0 + 1] - bv) * LOG2E);
        o.z = exp2_fast((acc[g][rs][2] + sb[n0 + 2] - bv) * LOG2E);
        o.w = exp2_fast((acc[g][rs][3] + sb[n0 + 3] - bv) * LOG2E);
        *(float4*)(orow + n0) = o;
      } else if (n0 == 100) {
        float4 o = {(bv - ls) * LOG2E, 0.f, 0.f, 0.f};
        *(float4*)(orow + n0) = o;
      }
    }
  }
}

// ---------------- kernel 3: CTC forward DP, 2 samples/wave, compiler-visible loads ----------------
// Plain C loads (compiler inserts correct counted vmcnt; spills are safe) pinned
// with sched_barrier(0). Two independent chains hide dependent-VALU latency.
#define DEPTH 8

#define LOADP(PX, PY, tb_)                                                \
  _Pragma("unroll") for (int i = 0; i < DEPTH; ++i) {                     \
    int tt = (tb_) + i;                                                   \
    int tx = (tt < ilenX) ? tt : (ilenX - 1);                             \
    int ty = (tt < ilenY) ? tt : (ilenY - 1);                             \
    PX[i] = *(const float2*)(lpbX + (size_t)tx * 112 + pidx);             \
    PY[i] = *(const float2*)(lpbY + (size_t)ty * 112 + pidx);             \
  }

#define DP1(A0, A1, A2, A3, m1_, m3_, dneg, cbs, PV)                      \
  {                                                                       \
    float pm1 = dpp_shr1(A3);                                             \
    pm1 = ldexp_fast(pm1, dneg);                                          \
    float px = (PV).x * vmx;                                              \
    float u1 = A0 + A1; u1 = fmaf(pm1, m1_, u1);                          \
    float u3 = A2 + A3; u3 = fmaf(A1, m3_, u3);                           \
    A0 = A0 + pm1;                                                        \
    A2 = A1 + A2;                                                         \
    A1 = u1 * px;                                                         \
    A3 = u3 * (PV).y;                                                     \
    cbs += (PV).x;                                                        \
  }

#define DP1M(A0, A1, A2, A3, m1_, m3_, dneg, cbs, PV, act)                \
  {                                                                       \
    float pm1 = dpp_shr1(A3);                                             \
    pm1 = ldexp_fast(pm1, dneg);                                          \
    float px = (PV).x * vmx;                                              \
    float u1 = A0 + A1; u1 = fmaf(pm1, m1_, u1);                          \
    float u3 = A2 + A3; u3 = fmaf(A1, m3_, u3);                           \
    float t0 = A0 + pm1;                                                  \
    float t2 = A1 + A2;                                                   \
    float t1 = u1 * px;                                                   \
    float t3 = u3 * (PV).y;                                               \
    if (act) { A0 = t0; A1 = t1; A2 = t2; A3 = t3; cbs += (PV).x; }       \
  }

#define RES1(A0, A1, A2, A3, lsc, dneg)                                   \
  {                                                                       \
    float m_ = fmaxf(fmaxf(A0, A1), fmaxf(A2, A3));                       \
    int u_ = __builtin_bit_cast(int, m_);                                 \
    int e_ = u_ >> 23;                                                    \
    bool nz_ = (u_ != 0);                                                 \
    float sc_ = nz_ ? __builtin_bit_cast(float, (254 - e_) << 23) : 1.f;  \
    A0 *= sc_; A1 *= sc_; A2 *= sc_; A3 *= sc_;                           \
    lsc += nz_ ? (float)(e_ - 127) : 0.f;                                 \
    float lp_ = dpp_shr1_keep(lsc);                                       \
    lsc = nz_ ? lsc : lp_;                                                \
    int d_ = (int)(lp_ - lsc);                                            \
    dneg = d_ > 126 ? 126 : d_;                                           \
  }

#define PH2(PX, PY)                                                       \
  _Pragma("unroll") for (int i = 0; i < DEPTH; ++i) {                     \
    DP1(X0, X1, X2, X3, mX1, mX3, dnegX, cbsX, PX[i])                     \
    DP1(Y0, Y1, Y2, Y3, mY1, mY3, dnegY, cbsY, PY[i])                     \
    if ((i & 3) == 3) {                                                   \
      RES1(X0, X1, X2, X3, lscX, dnegX)                                   \
      RES1(Y0, Y1, Y2, Y3, lscY, dnegY)                                   \
    }                                                                     \
  }

#define PH2M(PX, PY, tb_)                                                 \
  _Pragma("unroll") for (int i = 0; i < DEPTH; ++i) {                     \
    bool aX = ((tb_) + i) < ilenX, aY = ((tb_) + i) < ilenY;              \
    DP1M(X0, X1, X2, X3, mX1, mX3, dnegX, cbsX, PX[i], aX)                \
    DP1M(Y0, Y1, Y2, Y3, mY1, mY3, dnegY, cbsY, PY[i], aY)                \
    if ((i & 3) == 3) {                                                   \
      RES1(X0, X1, X2, X3, lscX, dnegX)                                   \
      RES1(Y0, Y1, Y2, Y3, lscY, dnegY)                                   \
    }                                                                     \
  }

__launch_bounds__(64)
__global__ void ctc_dp_kernel(const float* __restrict__ lp, const int* __restrict__ ys,
                              const int* __restrict__ hlens, const int* __restrict__ olens,
                              float* __restrict__ loss, int T, int L) {
  __shared__ float arr[2][256];
  __shared__ float lscarr[2][64];
  const int b0 = blockIdx.x * 2;
  const int lane = threadIdx.x;
  const int ilenX = hlens[b0], ilenY = hlens[b0 + 1];
  const int Smax = 2 * L;

  float mX1, mX3, mY1, mY3;
  {
    int s1 = 4 * lane + 1, s3 = 4 * lane + 3;
    int i1 = min((s1 - 1) >> 1, L - 1), i1p = max(0, min((s1 - 3) >> 1, L - 1));
    int i3 = min((s3 - 1) >> 1, L - 1), i3p = max(0, min((s3 - 3) >> 1, L - 1));
    bool v1 = (s1 <= Smax) && (s1 >= 3), v3 = (s3 <= Smax) && (s3 >= 3);
    int a = ys[b0 * L + i1], ap = ys[b0 * L + i1p];
    int c = ys[b0 * L + i3], cp = ys[b0 * L + i3p];
    mX1 = (v1 && (a != ap)) ? 1.f : 0.f;
    mX3 = (v3 && (c != cp)) ? 1.f : 0.f;
    a = ys[(b0 + 1) * L + i1]; ap = ys[(b0 + 1) * L + i1p];
    c = ys[(b0 + 1) * L + i3]; cp = ys[(b0 + 1) * L + i3p];
    mY1 = (v1 && (a != ap)) ? 1.f : 0.f;
    mY3 = (v3 && (c != cp)) ? 1.f : 0.f;
  }
  const int lim = (Smax - 3) >> 2;
  const int pidx = (lane <= lim) ? 2 * lane : ((lane == lim + 1) ? L : (L + 2));
  const float vmx = (lane == lim + 1) ? 0.f : 1.f;

  const float* lpbX = lp + (size_t)(b0 * T) * 112;
  const float* lpbY = lp + (size_t)((b0 + 1) * T) * 112;

  float X0 = (lane == 0) ? 1.f : 0.f, X1 = 0.f, X2 = 0.f, X3 = 0.f;
  float Y0 = (lane == 0) ? 1.f : 0.f, Y1 = 0.f, Y2 = 0.f, Y3 = 0.f;
  float lscX = 0.f, cbsX = 0.f, lscY = 0.f, cbsY = 0.f;
  int dnegX = 0, dnegY = 0;

  float2 XA[DEPTH], XB[DEPTH], YA[DEPTH], YB[DEPTH];
  const int maxI = max(ilenX, ilenY), minI = min(ilenX, ilenY);
  const int nph = (maxI + DEPTH - 1) / DEPTH;

  LOADP(XA, YA, 0)
  __builtin_amdgcn_sched_barrier(0);
  for (int k = 0; k < nph; ++k) {
    const int tb = k * DEPTH;
    const bool needM = (tb + DEPTH) > minI;
    if (k & 1) {
      if (k + 1 < nph) { LOADP(XA, YA, tb + DEPTH) }
      __builtin_amdgcn_sched_barrier(0);
      if (needM) { PH2M(XB, YB, tb) } else { PH2(XB, YB) }
    } else {
      if (k + 1 < nph) { LOADP(XB, YB, tb + DEPTH) }
      __builtin_amdgcn_sched_barrier(0);
      if (needM) { PH2M(XA, YA, tb) } else { PH2(XA, YA) }
    }
    __builtin_amdgcn_sched_barrier(0);
  }

  arr[0][lane * 4 + 0] = X0; arr[0][lane * 4 + 1] = X1;
  arr[0][lane * 4 + 2] = X2; arr[0][lane * 4 + 3] = X3;
  arr[1][lane * 4 + 0] = Y0; arr[1][lane * 4 + 1] = Y1;
  arr[1][lane * 4 + 2] = Y2; arr[1][lane * 4 + 3] = Y3;
  lscarr[0][lane] = lscX; lscarr[1][lane] = lscY;
  float cb0 = __builtin_bit_cast(float,
      __builtin_amdgcn_readlane(__builtin_bit_cast(int, cbsX), lim + 1));
  float cb1 = __builtin_bit_cast(float,
      __builtin_amdgcn_readlane(__builtin_bit_cast(int, cbsY), lim + 1));
  __syncthreads();
  if (lane == 0) {
#pragma unroll
    for (int s = 0; s < 2; ++s) {
      int ol = olens[b0 + s];
      float aN = arr[s][2 * ol], aNm = arr[s][2 * ol - 1];
      float l1 = lscarr[s][(2 * ol) >> 2], l2 = lscarr[s][(2 * ol - 1) >> 2];
      float mm = fmaxf(l1, l2);
      float v = ldexp_fast(aN, (int)(l1 - mm)) + ldexp_fast(aNm, (int)(l2 - mm));
      loss[b0 + s] = -LN2 * (log2_fast(v) + mm + (s ? cb1 : cb0));
    }
  }
}

__global__ void finalize_kernel(const float* __restrict__ loss, float* __restrict__ out, int B) {
  float v = ((int)threadIdx.x < B) ? loss[threadIdx.x] : 0.f;
#pragma unroll
  for (int m = 1; m <= 32; m <<= 1) v += __shfl_xor(v, m);
  if (threadIdx.x == 0) out[0] = v / (float)B;
}

extern "C" void kernel_launch(void* const* d_in, const int* in_sizes, int n_in,
                              void* d_out, int out_size, void* d_ws, size_t ws_size,
                              hipStream_t stream) {
  const float* hs    = (const float*)d_in[0];
  const int*   hlens = (const int*)d_in[1];
  const int*   ys    = (const int*)d_in[2];
  const int*   olens = (const int*)d_in[3];
  const float* W     = (const float*)d_in[4];
  const float* bias  = (const float*)d_in[5];

  int B = in_sizes[1];              // 16
  int L = in_sizes[2] / B;          // 100
  int V = in_sizes[5];              // 5000
  int D = in_sizes[4] / V;          // 512
  int T = in_sizes[0] / (B * D);    // 800
  int Vp = (V + 63) & ~63;          // 5056
  int M = B * T;                    // 12800
  int NC_tot = Vp / 32;             // 158

  char* ws = (char*)d_ws;
  unsigned short* Hbf = (unsigned short*)ws;
  size_t off = (size_t)M * D * 2;
  unsigned short* Wbf = (unsigned short*)(ws + off);
  off += (size_t)Vp * D * 2;
  float* lse = (float*)(ws + off);
  off += (size_t)M * 4;
  off = (off + 255) & ~(size_t)255;
  float2* lse_p = (float2*)(ws + off);
  off += (size_t)NS * M * 8;
  off = (off + 255) & ~(size_t)255;
  float* lp = (float*)(ws + off);
  off += (size_t)M * 112 * 4;
  float* loss = (float*)(ws + off);

  int n4h = M * D / 4;
  cvt_h_kernel<<<(n4h + 255) / 256, 256, 0, stream>>>(hs, Hbf, n4h);
  int n4w = Vp * D / 4;
  cvt_w_kernel<<<(n4w + 255) / 256, 256, 0, stream>>>(W, Wbf, V, D / 4, n4w);
  lse_kernel<<<100 * NS, 256, 0, stream>>>(Hbf, Wbf, bias, lse_p, V, NC_tot, M);
  lse_merge<<<(M + 255) / 256, 256, 0, stream>>>(lse_p, lse, M);
  sel_kernel<<<B * 7, 256, 0, stream>>>(Hbf, Wbf, bias, ys, lse, lp, B, T, L);
  ctc_dp_kernel<<<B / 2, 64, 0, stream>>>(lp, ys, hlens, olens, loss, T, L);
  finalize_kernel<<<1, 64, 0, stream>>>(loss, (float*)d_out, B);
}

// Round 13
// 161.692 us; speedup vs baseline: 1.8585x; 1.2354x over previous
//
#include <hip/hip_runtime.h>
#include <stdint.h>

#define NEG (-1e30f)
#define LOG2E 1.4426950408889634f
#define LN2 0.6931471805599453f
#define NS 5      // vocab splits for lse
#define CPB 32    // 32-voc chunks per split (ceil(158/5))

typedef __attribute__((ext_vector_type(8))) short bf16x8;
typedef __attribute__((ext_vector_type(4))) float f32x4;

__device__ __forceinline__ unsigned short f2bf(float f) {
  unsigned u = __builtin_bit_cast(unsigned, f);
  unsigned r = u + 0x7FFFu + ((u >> 16) & 1u);
  return (unsigned short)(r >> 16);
}
__device__ __forceinline__ float exp2_fast(float x) {
  float r; asm("v_exp_f32 %0, %1" : "=v"(r) : "v"(x)); return r;
}
__device__ __forceinline__ float log2_fast(float x) {
  float r; asm("v_log_f32 %0, %1" : "=v"(r) : "v"(x)); return r;
}
__device__ __forceinline__ float ldexp_fast(float x, int n) {
  float r; asm("v_ldexp_f32 %0, %1, %2" : "=v"(r) : "v"(x), "v"(n)); return r;
}
// lane l gets lane l-1's value; lane 0 gets 0
__device__ __forceinline__ float dpp_shr1(float x) {
  int r = __builtin_amdgcn_update_dpp(0, __builtin_bit_cast(int, x),
                                      0x138, 0xf, 0xf, false);  // wave_shr:1
  return __builtin_bit_cast(float, r);
}
// lane l gets lane l-1's value; lane 0 keeps its own
__device__ __forceinline__ float dpp_shr1_keep(float x) {
  int xi = __builtin_bit_cast(int, x);
  int r = __builtin_amdgcn_update_dpp(xi, xi, 0x138, 0xf, 0xf, false);
  return __builtin_bit_cast(float, r);
}

// ---------------- prep: f32 -> bf16 ----------------
__global__ void cvt_h_kernel(const float* __restrict__ src,
                             unsigned short* __restrict__ dst, int n4) {
  int i = blockIdx.x * 256 + threadIdx.x;
  if (i >= n4) return;
  float4 v = ((const float4*)src)[i];
  ushort4 o;
  o.x = f2bf(v.x); o.y = f2bf(v.y); o.z = f2bf(v.z); o.w = f2bf(v.w);
  ((ushort4*)dst)[i] = o;
}

__global__ void cvt_w_kernel(const float* __restrict__ W,
                             unsigned short* __restrict__ dst,
                             int V, int D4, int n4) {
  int i = blockIdx.x * 256 + threadIdx.x;
  if (i >= n4) return;
  int row = i / D4;
  ushort4 o = {0, 0, 0, 0};
  if (row < V) {
    float4 v = ((const float4*)W)[i];
    o.x = f2bf(v.x); o.y = f2bf(v.y); o.z = f2bf(v.z); o.w = f2bf(v.w);
  }
  ((ushort4*)dst)[i] = o;
}

// ---------------- kernel 1: fused GEMM + online logsumexp over V ----------------
__device__ __forceinline__ void stage32(const unsigned short* Wbf, unsigned char* sbuf,
                                        float* sb, const float* bias, int c, int V, int tid) {
  const unsigned char* base = (const unsigned char*)Wbf + ((size_t)c << 15);
#pragma unroll
  for (int i = 0; i < 8; ++i) {
    int dest = (i << 12) + (tid << 4);
    int row = dest >> 10;
    int src = (row << 10) + ((dest & 1023) ^ ((row & 15) << 4));
    __builtin_amdgcn_global_load_lds(
        (const __attribute__((address_space(1))) unsigned int*)(base + src),
        (__attribute__((address_space(3))) unsigned int*)(sbuf + dest), 16, 0, 0);
  }
  if (tid < 32) {
    int vg = (c << 5) + tid;
    sb[tid] = (vg < V) ? bias[vg] : 0.f;
  }
}

__launch_bounds__(256, 2)
__global__ void lse_kernel(const unsigned short* __restrict__ Hbf,
                           const unsigned short* __restrict__ Wbf,
                           const float* __restrict__ bias,
                           float2* __restrict__ lse_p,
                           int V, int NC_tot, int M) {
  __shared__ __align__(16) unsigned char sW[2][32768];
  __shared__ float sbias[2][32];
  const int tid = threadIdx.x;
  const int lane = tid & 63;
  const int w = tid >> 6;
  const int vl = lane & 15, kq = lane >> 4;
  const int mblk = blockIdx.x % 100;
  const int split = blockIdx.x / 100;
  const int c0 = split * CPB;
  const int c1 = min(NC_tot, c0 + CPB);
  const int rowbase = mblk * 128 + w * 32;

  bf16x8 bq0[16], bq1[16];
  {
    const unsigned short* h0 = Hbf + (size_t)(rowbase + vl) * 512 + kq * 8;
    const unsigned short* h1 = Hbf + (size_t)(rowbase + 16 + vl) * 512 + kq * 8;
#pragma unroll
    for (int ks = 0; ks < 16; ++ks) {
      bq0[ks] = *(const bf16x8*)(h0 + ks * 32);
      bq1[ks] = *(const bf16x8*)(h1 + ks * 32);
    }
  }

  stage32(Wbf, sW[0], sbias[0], bias, c0, V, tid);
  int cur = 0;
  float mx0 = NEG, sm0 = 0.f, mx1 = NEG, sm1 = 0.f;

  for (int c = c0; c < c1; ++c) {
    asm volatile("s_waitcnt vmcnt(0)" ::: "memory");
    __syncthreads();
    if (c + 1 < c1) stage32(Wbf, sW[cur ^ 1], sbias[cur ^ 1], bias, c + 1, V, tid);

    f32x4 a00 = 0.f, a01 = 0.f, a10 = 0.f, a11 = 0.f;
#pragma unroll
    for (int ks = 0; ks < 16; ++ks) {
      int inrow = (ks * 64 + kq * 16) ^ (vl << 4);
      bf16x8 A0 = *(const bf16x8*)(&sW[cur][(vl << 10) + inrow]);
      bf16x8 A1 = *(const bf16x8*)(&sW[cur][16384 + (vl << 10) + inrow]);
      a00 = __builtin_amdgcn_mfma_f32_16x16x32_bf16(A0, bq0[ks], a00, 0, 0, 0);
      a01 = __builtin_amdgcn_mfma_f32_16x16x32_bf16(A0, bq1[ks], a01, 0, 0, 0);
      a10 = __builtin_amdgcn_mfma_f32_16x16x32_bf16(A1, bq0[ks], a10, 0, 0, 0);
      a11 = __builtin_amdgcn_mfma_f32_16x16x32_bf16(A1, bq1[ks], a11, 0, 0, 0);
    }
    float lg0[8], lg1[8];
#pragma unroll
    for (int g = 0; g < 2; ++g)
#pragma unroll
      for (int j = 0; j < 4; ++j) {
        int vloc = g * 16 + kq * 4 + j;
        bool ok = (c * 32 + vloc) < V;
        float bb = sbias[cur][vloc];
        float x0 = (g == 0) ? a00[j] : a10[j];
        float x1 = (g == 0) ? a01[j] : a11[j];
        lg0[g * 4 + j] = ok ? (x0 + bb) : NEG;
        lg1[g * 4 + j] = ok ? (x1 + bb) : NEG;
      }
    float lm0 = lg0[0], lm1 = lg1[0];
#pragma unroll
    for (int i = 1; i < 8; ++i) { lm0 = fmaxf(lm0, lg0[i]); lm1 = fmaxf(lm1, lg1[i]); }
    float nm0 = fmaxf(mx0, lm0), nm1 = fmaxf(mx1, lm1);
    float s0 = 0.f, s1 = 0.f;
#pragma unroll
    for (int i = 0; i < 8; ++i) { s0 += __expf(lg0[i] - nm0); s1 += __expf(lg1[i] - nm1); }
    sm0 = sm0 * __expf(mx0 - nm0) + s0;  mx0 = nm0;
    sm1 = sm1 * __expf(mx1 - nm1) + s1;  mx1 = nm1;
    cur ^= 1;
  }

#pragma unroll
  for (int d = 16; d <= 32; d <<= 1) {
    float omx = __shfl_xor(mx0, d), osm = __shfl_xor(sm0, d);
    float nm = fmaxf(mx0, omx);
    sm0 = sm0 * __expf(mx0 - nm) + osm * __expf(omx - nm); mx0 = nm;
    omx = __shfl_xor(mx1, d); osm = __shfl_xor(sm1, d);
    nm = fmaxf(mx1, omx);
    sm1 = sm1 * __expf(mx1 - nm) + osm * __expf(omx - nm); mx1 = nm;
  }
  if (lane < 16) {
    lse_p[(size_t)split * M + rowbase + vl]      = make_float2(mx0, sm0);
    lse_p[(size_t)split * M + rowbase + 16 + vl] = make_float2(mx1, sm1);
  }
}

__global__ void lse_merge(const float2* __restrict__ lse_p, float* __restrict__ lse, int M) {
  int i = blockIdx.x * 256 + threadIdx.x;
  if (i >= M) return;
  float mx = NEG, sm = 0.f;
#pragma unroll
  for (int s = 0; s < NS; ++s) {
    float2 p = lse_p[(size_t)s * M + i];
    float nm = fmaxf(mx, p.x);
    sm = sm * __expf(mx - nm) + p.y * __expf(p.x - nm);
    mx = nm;
  }
  lse[i] = mx + __logf(sm);
}

// ---------------- kernel 2: selected logits via gathered-W MFMA GEMM ----------------
// Output row (stride 112): [0..L-1] = exp(logit_lab - logit_blank)  (linear ratio)
//                          [100]    = cb = (logit_blank - lse)*log2e (log2 domain)
//                          [101..103] = 0  (zero pad read by invalid dp lanes)
__launch_bounds__(256, 1)
__global__ void sel_kernel(const unsigned short* __restrict__ Hbf,
                           const unsigned short* __restrict__ Wbf,
                           const float* __restrict__ bias,
                           const int* __restrict__ ys,
                           const float* __restrict__ lse,
                           float* __restrict__ lp,
                           int B, int T, int L) {
  __shared__ __align__(16) unsigned char sWs[114688];  // 112 rows x 1KB
  __shared__ float sb[112];
  const int tid = threadIdx.x, lane = tid & 63, w = tid >> 6;
  const int vl = lane & 15, kq = lane >> 4;
  const int b = blockIdx.x / 7;
  const int mt = blockIdx.x % 7;

  int vocs[28];
#pragma unroll
  for (int i = 0; i < 28; ++i) {
    int n = w * 28 + i;
    vocs[i] = (n < L) ? ys[b * L + n] : 0;
  }
#pragma unroll
  for (int i = 0; i < 28; ++i) {
    int n = w * 28 + i;
    const unsigned char* src = (const unsigned char*)Wbf + ((size_t)vocs[i] << 10);
    int soff = (lane << 4) ^ ((n & 15) << 4);
    __builtin_amdgcn_global_load_lds(
        (const __attribute__((address_space(1))) unsigned int*)(src + soff),
        (__attribute__((address_space(3))) unsigned int*)(sWs + (n << 10) + (lane << 4)), 16, 0, 0);
  }
  if (tid < 112) {
    int voc = (tid < L) ? ys[b * L + tid] : 0;
    sb[tid] = bias[voc];
  }

  const int trow0 = mt * 128 + w * 32;
  bf16x8 bq0[16], bq1[16];
  {
    int t0 = min(trow0 + vl, T - 1), t1 = min(trow0 + 16 + vl, T - 1);
    const unsigned short* h0 = Hbf + (size_t)(b * T + t0) * 512 + kq * 8;
    const unsigned short* h1 = Hbf + (size_t)(b * T + t1) * 512 + kq * 8;
#pragma unroll
    for (int ks = 0; ks < 16; ++ks) {
      bq0[ks] = *(const bf16x8*)(h0 + ks * 32);
      bq1[ks] = *(const bf16x8*)(h1 + ks * 32);
    }
  }
  float ls0 = lse[b * T + min(trow0 + vl, T - 1)];
  float ls1 = lse[b * T + min(trow0 + 16 + vl, T - 1)];

  asm volatile("s_waitcnt vmcnt(0)" ::: "memory");
  __syncthreads();

  f32x4 acc[7][2];
#pragma unroll
  for (int g = 0; g < 7; ++g) { acc[g][0] = 0.f; acc[g][1] = 0.f; }
#pragma unroll
  for (int ks = 0; ks < 16; ++ks) {
    int inrow = (ks * 64 + kq * 16) ^ (vl << 4);
#pragma unroll
    for (int g = 0; g < 7; ++g) {
      bf16x8 A = *(const bf16x8*)(&sWs[((g * 16 + vl) << 10) + inrow]);
      acc[g][0] = __builtin_amdgcn_mfma_f32_16x16x32_bf16(A, bq0[ks], acc[g][0], 0, 0, 0);
      acc[g][1] = __builtin_amdgcn_mfma_f32_16x16x32_bf16(A, bq1[ks], acc[g][1], 0, 0, 0);
    }
  }

  // blank logit+bias lives at n=100 (g=6, kq=1, j=0); broadcast from lane 16+vl
  float bv0, bv1;
  {
    float m0 = acc[6][0][0] + sb[100];
    float m1 = acc[6][1][0] + sb[100];
    bv0 = __shfl(m0, 16 + vl, 64);
    bv1 = __shfl(m1, 16 + vl, 64);
  }

#pragma unroll
  for (int rs = 0; rs < 2; ++rs) {
    int trow = trow0 + rs * 16 + vl;
    if (trow >= T) continue;
    float ls = rs ? ls1 : ls0;
    float bv = rs ? bv1 : bv0;
    float* orow = lp + (size_t)(b * T + trow) * 112;
#pragma unroll
    for (int g = 0; g < 7; ++g) {
      int n0 = g * 16 + kq * 4;
      if (n0 < 100) {
        float4 o;
        o.x = exp2_fast((acc[g][rs][0] + sb[n0 + 0] - bv) * LOG2E);
        o.y = exp2_fast((acc[g][rs][1] + sb[n0 + 1] - bv) * LOG2E);
        o.z = exp2_fast((acc[g][rs][2] + sb[n0 + 2] - bv) * LOG2E);
        o.w = exp2_fast((acc[g][rs][3] + sb[n0 + 3] - bv) * LOG2E);
        *(float4*)(orow + n0) = o;
      } else if (n0 == 100) {
        float4 o = {(bv - ls) * LOG2E, 0.f, 0.f, 0.f};
        *(float4*)(orow + n0) = o;
      }
    }
  }
}

// ---------------- kernel 3: CTC forward DP, per-LANE scaled linear domain (R7 proven) ----------------
#define PH_ISSUE(P, Bk, tb_)                                              \
  _Pragma("unroll") for (int i = 0; i < 16; ++i) {                        \
    int tt = (tb_) + i; tt = (tt < ilen) ? tt : (ilen - 1);               \
    const float* r = lpb + (size_t)tt * 112;                              \
    asm volatile("global_load_dwordx2 %0, %1, off"                        \
                 : "=v"(P[i]) : "v"(r + pidx));                           \
    asm volatile("global_load_dword %0, %1, off"                          \
                 : "=v"(Bk[i]) : "v"(r + L));                             \
  }                                                                       \
  __builtin_amdgcn_sched_barrier(0);

#define DP_STEP(px_, py_, cb_)                                            \
  {                                                                       \
    float pm1 = dpp_shr1(A3);                                             \
    pm1 = ldexp_fast(pm1, dneg);                                          \
    float u1 = A0 + A1; u1 = fmaf(pm1, msk1, u1);                         \
    float u3 = A2 + A3; u3 = fmaf(A1, msk3, u3);                          \
    A0 = A0 + pm1;                                                        \
    A2 = A1 + A2;                                                         \
    A1 = u1 * (px_);                                                      \
    A3 = u3 * (py_);                                                      \
    cbs += (cb_);                                                         \
  }

#define DP_STEP_M(px_, py_, cb_, act)                                     \
  {                                                                       \
    float pm1 = dpp_shr1(A3);                                             \
    pm1 = ldexp_fast(pm1, dneg);                                          \
    float u1 = A0 + A1; u1 = fmaf(pm1, msk1, u1);                         \
    float u3 = A2 + A3; u3 = fmaf(A1, msk3, u3);                          \
    float t0 = A0 + pm1;                                                  \
    float t2 = A1 + A2;                                                   \
    float t1 = u1 * (px_);                                                \
    float t3 = u3 * (py_);                                                \
    if (act) { A0 = t0; A1 = t1; A2 = t2; A3 = t3; cbs += (cb_); }        \
  }

#define RESCALE                                                           \
  {                                                                       \
    float m_ = fmaxf(fmaxf(A0, A1), fmaxf(A2, A3));                       \
    int u_ = __builtin_bit_cast(int, m_);                                 \
    int e_ = u_ >> 23;                                                    \
    bool nz_ = (u_ != 0);                                                 \
    float sc_ = nz_ ? __builtin_bit_cast(float, (254 - e_) << 23) : 1.f;  \
    A0 *= sc_; A1 *= sc_; A2 *= sc_; A3 *= sc_;                           \
    lsc += nz_ ? (float)(e_ - 127) : 0.f;                                 \
    float lp_ = dpp_shr1_keep(lsc);                                       \
    lsc = nz_ ? lsc : lp_;                                                \
    int d_ = (int)(lp_ - lsc);                                            \
    dneg = d_ > 126 ? 126 : d_;                                           \
  }

#define PH_COMP(P, Bk)                                                    \
  _Pragma("unroll") for (int i = 0; i < 16; ++i) {                        \
    DP_STEP(P[i].x, P[i].y, Bk[i])                                        \
    if ((i & 3) == 3) RESCALE                                             \
  }

#define PH_COMP_M(P, Bk, tb_)                                             \
  _Pragma("unroll") for (int i = 0; i < 16; ++i) {                        \
    DP_STEP_M(P[i].x, P[i].y, Bk[i], ((tb_) + i) < ilen)                  \
    if ((i & 3) == 3) RESCALE                                             \
  }

__launch_bounds__(64)
__global__ void ctc_dp_kernel(const float* __restrict__ lp, const int* __restrict__ ys,
                              const int* __restrict__ hlens, const int* __restrict__ olens,
                              float* __restrict__ loss, int T, int L) {
  __shared__ float arr[256];
  __shared__ float lscarr[64];
  const int b = blockIdx.x;
  const int lane = threadIdx.x;
  const int ilen = hlens[b];
  const int Smax = 2 * L;

  float msk1, msk3;
  {
    int s1 = 4 * lane + 1, s3 = 4 * lane + 3;
    int i1 = min((s1 - 1) >> 1, L - 1), i1p = max(0, min((s1 - 3) >> 1, L - 1));
    int i3 = min((s3 - 1) >> 1, L - 1), i3p = max(0, min((s3 - 3) >> 1, L - 1));
    int lab1 = ys[b * L + i1], lab1p = ys[b * L + i1p];
    int lab3 = ys[b * L + i3], lab3p = ys[b * L + i3p];
    msk1 = ((s1 <= Smax) && (s1 >= 3) && (lab1 != lab1p)) ? 1.f : 0.f;
    msk3 = ((s3 <= Smax) && (s3 >= 3) && (lab3 != lab3p)) ? 1.f : 0.f;
  }
  const int lim = (Smax - 3) >> 2;
  const int pidx = (lane <= lim) ? 2 * lane : (L + 2);

  const float* lpb = lp + (size_t)(b * T) * 112;

  float A0 = (lane == 0) ? 1.f : 0.f, A1 = 0.f, A2 = 0.f, A3 = 0.f;
  float lsc = 0.f, cbs = 0.f;
  int dneg = 0;

  float2 pA[16], pB[16], pC[16];
  float bA[16], bB[16], bC[16];
  const int nph = (ilen + 15) >> 4;

  PH_ISSUE(pA, bA, 0)
  PH_ISSUE(pB, bB, 16)
  for (int k = 0; k < nph; ++k) {
    const int tb = k << 4;
    asm volatile("s_waitcnt vmcnt(32)" ::: "memory");
    __builtin_amdgcn_sched_barrier(0);
    const int m3 = k - (k / 3) * 3;
    const bool lastm = (k == nph - 1);
    if (m3 == 0) {
      PH_ISSUE(pC, bC, tb + 32)
      if (lastm) { PH_COMP_M(pA, bA, tb) } else { PH_COMP(pA, bA) }
    } else if (m3 == 1) {
      PH_ISSUE(pA, bA, tb + 32)
      if (lastm) { PH_COMP_M(pB, bB, tb) } else { PH_COMP(pB, bB) }
    } else {
      PH_ISSUE(pB, bB, tb + 32)
      if (lastm) { PH_COMP_M(pC, bC, tb) } else { PH_COMP(pC, bC) }
    }
  }
  asm volatile("s_waitcnt vmcnt(0)" ::: "memory");
  __builtin_amdgcn_sched_barrier(0);

  arr[lane * 4 + 0] = A0; arr[lane * 4 + 1] = A1;
  arr[lane * 4 + 2] = A2; arr[lane * 4 + 3] = A3;
  lscarr[lane] = lsc;
  __syncthreads();
  if (lane == 0) {
    int ol = olens[b];
    float aN = arr[2 * ol], aNm = arr[2 * ol - 1];
    float l1 = lscarr[(2 * ol) >> 2], l2 = lscarr[(2 * ol - 1) >> 2];
    float mm = fmaxf(l1, l2);
    float v = ldexp_fast(aN, (int)(l1 - mm)) + ldexp_fast(aNm, (int)(l2 - mm));
    loss[b] = -LN2 * (log2_fast(v) + mm + cbs);
  }
}

__global__ void finalize_kernel(const float* __restrict__ loss, float* __restrict__ out, int B) {
  float v = ((int)threadIdx.x < B) ? loss[threadIdx.x] : 0.f;
#pragma unroll
  for (int m = 1; m <= 32; m <<= 1) v += __shfl_xor(v, m);
  if (threadIdx.x == 0) out[0] = v / (float)B;
}

extern "C" void kernel_launch(void* const* d_in, const int* in_sizes, int n_in,
                              void* d_out, int out_size, void* d_ws, size_t ws_size,
                              hipStream_t stream) {
  const float* hs    = (const float*)d_in[0];
  const int*   hlens = (const int*)d_in[1];
  const int*   ys    = (const int*)d_in[2];
  const int*   olens = (const int*)d_in[3];
  const float* W     = (const float*)d_in[4];
  const float* bias  = (const float*)d_in[5];

  int B = in_sizes[1];              // 16
  int L = in_sizes[2] / B;          // 100
  int V = in_sizes[5];              // 5000
  int D = in_sizes[4] / V;          // 512
  int T = in_sizes[0] / (B * D);    // 800
  int Vp = (V + 63) & ~63;          // 5056
  int M = B * T;                    // 12800
  int NC_tot = Vp / 32;             // 158

  char* ws = (char*)d_ws;
  unsigned short* Hbf = (unsigned short*)ws;
  size_t off = (size_t)M * D * 2;
  unsigned short* Wbf = (unsigned short*)(ws + off);
  off += (size_t)Vp * D * 2;
  float* lse = (float*)(ws + off);
  off += (size_t)M * 4;
  off = (off + 255) & ~(size_t)255;
  float2* lse_p = (float2*)(ws + off);
  off += (size_t)NS * M * 8;
  off = (off + 255) & ~(size_t)255;
  float* lp = (float*)(ws + off);
  off += (size_t)M * 112 * 4;
  float* loss = (float*)(ws + off);

  int n4h = M * D / 4;
  cvt_h_kernel<<<(n4h + 255) / 256, 256, 0, stream>>>(hs, Hbf, n4h);
  int n4w = Vp * D / 4;
  cvt_w_kernel<<<(n4w + 255) / 256, 256, 0, stream>>>(W, Wbf, V, D / 4, n4w);
  lse_kernel<<<100 * NS, 256, 0, stream>>>(Hbf, Wbf, bias, lse_p, V, NC_tot, M);
  lse_merge<<<(M + 255) / 256, 256, 0, stream>>>(lse_p, lse, M);
  sel_kernel<<<B * 7, 256, 0, stream>>>(Hbf, Wbf, bias, ys, lse, lp, B, T, L);
  ctc_dp_kernel<<<B, 64, 0, stream>>>(lp, ys, hlens, olens, loss, T, L);
  finalize_kernel<<<1, 64, 0, stream>>>(loss, (float*)d_out, B);
}